// Round 4
// baseline (259.367 us; speedup 1.0000x reference)
//
#include <hip/hip_runtime.h>
#include <cmath>

// B=4, S=4096, D_IN=1024, D_K=D_V=64
constexpr int B_  = 4;
constexpr int S_  = 4096;
constexpr int DIN = 1024;
constexpr int DH  = 64;

typedef short bf16x8 __attribute__((ext_vector_type(8)));
typedef float f32x4  __attribute__((ext_vector_type(4)));

#define GPTR(p) (const __attribute__((address_space(1))) unsigned int*)(p)
#define LPTR(p) (__attribute__((address_space(3))) unsigned int*)(p)
#define LDSB8(p) (*(const __attribute__((address_space(3))) bf16x8*)(p))

// fp32 -> bf16 RNE, raw bits
__device__ __forceinline__ ushort f2bf(float x) {
    unsigned int u = __float_as_uint(x);
    return (ushort)((u + 0x7FFFu + ((u >> 16) & 1u)) >> 16);
}

__device__ __forceinline__ bf16x8 cvt8(f32x4 a, f32x4 b) {
    union { bf16x8 v; ushort u[8]; } r;
    r.u[0] = f2bf(a[0]); r.u[1] = f2bf(a[1]); r.u[2] = f2bf(a[2]); r.u[3] = f2bf(a[3]);
    r.u[4] = f2bf(b[0]); r.u[5] = f2bf(b[1]); r.u[6] = f2bf(b[2]); r.u[7] = f2bf(b[3]);
    return r.v;
}

// softmax scale 1/8 with log2(e) folded in (softmax via exp2)
#define QSCALE 0.18033688011112042f

// ---------------------------------------------------------------------------
// setup_w: W[1024][64] fp32 -> FRAGMENT-ORDERED bf16 image (unchanged, works).
// Frag F = ((it*2+ks)*4+nt)*64+lane holds the 16B MFMA B-fragment.
// ---------------------------------------------------------------------------
__global__ __launch_bounds__(256) void setup_w(
    const float* __restrict__ Wq, const float* __restrict__ Wk,
    const float* __restrict__ Wv, ushort* __restrict__ Wt_g)
{
    const int y = blockIdx.y;
    const float* W = (y == 0) ? Wq : (y == 1) ? Wk : Wv;
    const int g    = blockIdx.x * 256 + threadIdx.x;
    const int lane = g & 63;
    const int nt   = (g >> 6) & 3;
    const int ks   = (g >> 8) & 1;
    const int it   = g >> 9;
    const int m    = lane & 15;
    const int quad = lane >> 4;
    const int n    = nt * 16 + m;
    const int k0   = it * 64 + (ks * 4 + quad) * 8;
    union { uint4 q; ushort u[8]; } r;
    #pragma unroll
    for (int i = 0; i < 8; ++i) r.u[i] = f2bf(W[(size_t)(k0 + i) * DH + n]);
    *(uint4*)(Wt_g + ((size_t)y << 16) + (size_t)g * 8) = r.q;
}

// ---------------------------------------------------------------------------
// Projection v4. Post-mortem r0-r3: four schedules, identical 80us / 1.35TB/s.
// Common factor: in-flight bytes/CU capped ~144KB (LDS-window-bound in v3,
// RA-collapsed in v1/v2). Little's law under congested latency says delivered
// BW ~ inflight/latency -> we were queue-starved. m13's 6.3TB/s copy holds
// ~300KB/CU in flight. Fix: in-flight state lives in the REGISTER FILE
// (512KB/CU), pinned against the RA with asm-volatile global_load_dwordx4
// ("=v" outputs can't be re-ordered across the volatile counted s_waitcnt, so
// all 16 float4/wave MUST stay live -> RA cannot serialize). X: 4-window-deep
// asm register pipeline (16KB/wave). W: global_load_lds 4-deep LDS ring
// (shared vmcnt cadence: 6 ops/window, steady target vmcnt(18) = 3 windows).
// In-flight ~18KB/wave x 12 waves = 216KB/CU, 1.5x round-3.
// ---------------------------------------------------------------------------
#define WAITV(NLIT) asm volatile("s_waitcnt vmcnt(" NLIT ")" ::: "memory")
#define XLOAD(dst, OFFLIT) \
    asm volatile("global_load_dwordx4 %0, %1, off offset:" OFFLIT \
                 : "=v"(dst) : "v"(xa) : "memory")
// per window, lane(m,quad) owns row(m)'s bytes {0,16,128,144}+wi*256 past
// (row*1024 + quad*8) elems: ks=0 frag = (f0,f1), ks=1 frag = (f2,f3).
#define ISSUE_X(S) do { \
    XLOAD(xs##S##_0, "0");   XLOAD(xs##S##_1, "16"); \
    XLOAD(xs##S##_2, "128"); XLOAD(xs##S##_3, "144"); } while (0)
#define ISSUE_W(WI, S) do { \
    char* wdst_ = smem + (S) * 8192; \
    __builtin_amdgcn_global_load_lds(GPTR(wsrc + (size_t)((WI)*8 + w*2    )*1024 + lane*16), \
                                     LPTR(wdst_ + (w*2    )*1024 + lane*16), 16, 0, 0); \
    __builtin_amdgcn_global_load_lds(GPTR(wsrc + (size_t)((WI)*8 + w*2 + 1)*1024 + lane*16), \
                                     LPTR(wdst_ + (w*2 + 1)*1024 + lane*16), 16, 0, 0); } while (0)
#define COMPUTE(S) do { \
    const char* wb_ = smem + (S) * 8192; \
    const bf16x8 a0 = cvt8(xs##S##_0, xs##S##_1); \
    const bf16x8 a1 = cvt8(xs##S##_2, xs##S##_3); \
    _Pragma("unroll") \
    for (int nt = 0; nt < 4; ++nt) \
        acc[nt] = __builtin_amdgcn_mfma_f32_16x16x32_bf16(a0, LDSB8(wb_ + nt*1024 + lane*16), acc[nt], 0, 0, 0); \
    _Pragma("unroll") \
    for (int nt = 0; nt < 4; ++nt) \
        acc[nt] = __builtin_amdgcn_mfma_f32_16x16x32_bf16(a1, LDSB8(wb_ + (4+nt)*1024 + lane*16), acc[nt], 0, 0, 0); } while (0)
#define STEP(IT, S, VMLIT) do { \
    WAITV(VMLIT); \
    __builtin_amdgcn_sched_barrier(0); \
    __builtin_amdgcn_s_barrier(); \
    __builtin_amdgcn_sched_barrier(0); \
    COMPUTE(S); \
    __builtin_amdgcn_sched_barrier(0); \
    __builtin_amdgcn_s_barrier(); \
    __builtin_amdgcn_sched_barrier(0); \
    if ((IT) + 4 < 16) { \
        const uint64_t xa = xbase + (uint64_t)((IT) + 4) * 256; \
        ISSUE_X(S); \
        ISSUE_W((IT) + 4, S); \
    } } while (0)

__global__ __launch_bounds__(256, 3) void proj_kernel(
    const float* __restrict__ Xq, const float* __restrict__ Xk, const float* __restrict__ Xv,
    const float* __restrict__ bq, const float* __restrict__ bk, const float* __restrict__ bv,
    const ushort* __restrict__ Wt_g,
    ushort* __restrict__ Qb, ushort* __restrict__ Kb, ushort* __restrict__ Vt)
{
    __shared__ __align__(16) char smem[32768];   // W ring: 4 x 8KB (V-epi reuse)

    const int y = blockIdx.y;
    const float *X, *bias;
    if (y == 0)      { X = Xq; bias = bq; }
    else if (y == 1) { X = Xk; bias = bk; }
    else             { X = Xv; bias = bv; }

    const int tid  = threadIdx.x;
    const int w    = tid >> 6;
    const int lane = tid & 63;
    const int m    = lane & 15;
    const int quad = lane >> 4;
    const int row0 = blockIdx.x * 64;

    // bias first; drain so vmcnt bookkeeping starts at 0
    float bias_v[4];
    #pragma unroll
    for (int nt = 0; nt < 4; ++nt) bias_v[nt] = bias[nt * 16 + m];
    asm volatile("s_waitcnt vmcnt(0)" ::: "memory");
    __builtin_amdgcn_sched_barrier(0);

    const char*    wsrc  = (const char*)Wt_g + ((size_t)y << 17);   // y * 128KB
    const uint64_t xbase = (uint64_t)(uintptr_t)(X + (size_t)(row0 + w * 16 + m) * DIN + quad * 8);

    f32x4 xs0_0, xs0_1, xs0_2, xs0_3;
    f32x4 xs1_0, xs1_1, xs1_2, xs1_3;
    f32x4 xs2_0, xs2_1, xs2_2, xs2_3;
    f32x4 xs3_0, xs3_1, xs3_2, xs3_3;
    f32x4 acc[4] = {};

    // prologue: windows 0..3 into slots 0..3 (24 vmem ops in flight)
    { const uint64_t xa = xbase;                    ISSUE_X(0); ISSUE_W(0, 0); }
    { const uint64_t xa = xbase + 256;              ISSUE_X(1); ISSUE_W(1, 1); }
    { const uint64_t xa = xbase + 512;              ISSUE_X(2); ISSUE_W(2, 2); }
    { const uint64_t xa = xbase + 768;              ISSUE_X(3); ISSUE_W(3, 3); }

    // 16 k-windows; steady state: drain window IT (6 ops), keep 3 windows (18)
    STEP( 0, 0, "18"); STEP( 1, 1, "18"); STEP( 2, 2, "18"); STEP( 3, 3, "18");
    STEP( 4, 0, "18"); STEP( 5, 1, "18"); STEP( 6, 2, "18"); STEP( 7, 3, "18");
    STEP( 8, 0, "18"); STEP( 9, 1, "18"); STEP(10, 2, "18"); STEP(11, 3, "18");
    STEP(12, 0, "18"); STEP(13, 1, "12"); STEP(14, 2, "6");  STEP(15, 3, "0");

    if (y < 2) {
        ushort* Out = (y == 0) ? Qb : Kb;
        const float sc = (y == 0) ? QSCALE : 1.0f;
        #pragma unroll
        for (int nt = 0; nt < 4; ++nt)
            #pragma unroll
            for (int j = 0; j < 4; ++j) {
                const int r = row0 + w * 16 + quad * 4 + j;
                Out[(size_t)r * DH + nt * 16 + m] = f2bf((acc[nt][j] + bias_v[nt]) * sc);
            }
    } else {
        // V: transpose via LDS (reuse smem; loop fully drained + barrier-synced)
        __syncthreads();
        ushort* Vx = (ushort*)smem;                // pitch 72, chunk-XOR swizzled
        #pragma unroll
        for (int nt = 0; nt < 4; ++nt)
            #pragma unroll
            for (int j = 0; j < 4; ++j) {
                const int d = nt * 16 + m;
                const int s = w * 16 + quad * 4 + j;
                Vx[d * 72 + (((s >> 3) ^ (d & 7)) * 8) + (s & 7)] = f2bf(acc[nt][j] + bias_v[nt]);
            }
        __syncthreads();
        const int batch = row0 >> 12;
        const int s0    = row0 & 4095;
        for (int i = tid; i < 512; i += 256) {
            const int d = i >> 3, c = i & 7;
            const uint4 v = *(const uint4*)&Vx[d * 72 + ((c ^ (d & 7)) * 8)];
            *(uint4*)(Vt + ((size_t)batch * 64 + d) * S_ + s0 + c * 8) = v;
        }
    }
}

// ---------------------------------------------------------------------------
// Flash attention (unchanged this round — clean A/B on proj).
// ---------------------------------------------------------------------------
__global__ __launch_bounds__(256, 4) void attn_kernel(
    const ushort* __restrict__ Qb, const ushort* __restrict__ Kb,
    const ushort* __restrict__ Vt, float* __restrict__ Opart, float* __restrict__ Lpart)
{
    __shared__ ushort Ks[64 * 64];   // [j][d], chunk-XOR swizzled
    __shared__ ushort Vs[64 * 64];   // [d][j], chunk-XOR swizzled
    __shared__ ushort Pt[64 * 72];   // per-wave stripes, padded

    const int tid  = threadIdx.x;
    const int w    = tid >> 6;
    const int lane = tid & 63;
    const int m    = lane & 15;
    const int quad = lane >> 4;
    const int b    = blockIdx.z, jc = blockIdx.y, qt = blockIdx.x;
    const int q0   = qt * 64;

    bf16x8 qf[2];
    #pragma unroll
    for (int ks = 0; ks < 2; ++ks)
        qf[ks] = *(const bf16x8*)(Qb + (size_t)(b * S_ + q0 + w * 16 + m) * 64
                                     + ks * 32 + quad * 8);

    f32x4 acc_o[4] = {};
    float Lp[4] = {};

    const ushort* kbase = Kb + (size_t)b * S_ * 64;
    const ushort* vbase = Vt + (size_t)b * 64 * S_;

    for (int it = 0; it < 16; ++it) {
        const int jt = jc * 16 + it;
        __syncthreads();
        #pragma unroll
        for (int i = 0; i < 2; ++i) {
            const int slot = w * 128 + i * 64 + lane;
            const int j = slot >> 3, c = slot & 7;
            __builtin_amdgcn_global_load_lds(
                GPTR(kbase + (size_t)(jt * 64 + j) * 64 + ((c ^ (j & 7)) * 8)),
                LPTR(&Ks[(w * 128 + i * 64) * 8]), 16, 0, 0);
            __builtin_amdgcn_global_load_lds(
                GPTR(vbase + (size_t)j * S_ + jt * 64 + ((c ^ (j & 7)) * 8)),
                LPTR(&Vs[(w * 128 + i * 64) * 8]), 16, 0, 0);
        }
        __syncthreads();

        // S2 = (Q * 0.125*log2e) K^T
        f32x4 acc_s[4] = {};
        #pragma unroll
        for (int ks = 0; ks < 2; ++ks)
            #pragma unroll
            for (int jt4 = 0; jt4 < 4; ++jt4) {
                const int j = jt4 * 16 + m;
                const bf16x8 kf = *(const bf16x8*)&Ks[j * 64 + (((ks * 4 + quad) ^ (j & 7)) * 8)];
                acc_s[jt4] = __builtin_amdgcn_mfma_f32_16x16x32_bf16(
                    qf[ks], kf, acc_s[jt4], 0, 0, 0);
            }

        // P = exp2(S2); L += rowsum; P -> per-wave LDS stripe (bf16)
        #pragma unroll
        for (int jt4 = 0; jt4 < 4; ++jt4)
            #pragma unroll
            for (int r = 0; r < 4; ++r) {
                const float e = exp2f(acc_s[jt4][r]);
                Lp[r] += e;
                Pt[(w * 16 + quad * 4 + r) * 72 + jt4 * 16 + m] = f2bf(e);
            }

        // O += P V (same-wave LDS RAW, ordered by lgkmcnt)
        #pragma unroll
        for (int jc2 = 0; jc2 < 2; ++jc2) {
            const bf16x8 pf = *(const bf16x8*)&Pt[(w * 16 + m) * 72 + jc2 * 32 + quad * 8];
            #pragma unroll
            for (int dt = 0; dt < 4; ++dt) {
                const int d = dt * 16 + m;
                const bf16x8 vf = *(const bf16x8*)&Vs[d * 64 + (((jc2 * 4 + quad) ^ (d & 7)) * 8)];
                acc_o[dt] = __builtin_amdgcn_mfma_f32_16x16x32_bf16(pf, vf, acc_o[dt], 0, 0, 0);
            }
        }
    }

    #pragma unroll
    for (int r = 0; r < 4; ++r) {
        float s = Lp[r];
        #pragma unroll
        for (int off = 1; off < 16; off <<= 1)
            s += __shfl_xor(s, off, 64);
        Lp[r] = s;
    }

    const size_t bj = (size_t)(b * 4 + jc);
    float* Ob = Opart + (bj << 18);
    #pragma unroll
    for (int dt = 0; dt < 4; ++dt)
        #pragma unroll
        for (int r = 0; r < 4; ++r) {
            const int row = q0 + w * 16 + quad * 4 + r;
            Ob[(size_t)row * 64 + dt * 16 + m] = acc_o[dt][r];
        }
    if (m == 0) {
        #pragma unroll
        for (int r = 0; r < 4; ++r)
            Lpart[bj * 4096 + q0 + w * 16 + quad * 4 + r] = Lp[r];
    }
}

// ---------------------------------------------------------------------------
// Combine j-chunk partials: out = (sum_jc O) / (sum_jc L)
// ---------------------------------------------------------------------------
__global__ __launch_bounds__(256) void reduce_kernel(
    const float* __restrict__ Opart, const float* __restrict__ Lpart, float* __restrict__ out)
{
    const int g    = blockIdx.x * 256 + threadIdx.x;
    const int base = g << 2;
    const int b    = base >> 18;
    const int rem  = base & 0x3FFFF;
    const int q    = rem >> 6;
    float4 o = make_float4(0.f, 0.f, 0.f, 0.f);
    float  l = 0.f;
    #pragma unroll
    for (int jcc = 0; jcc < 4; ++jcc) {
        const float4 p = *(const float4*)(Opart + (((size_t)(b * 4 + jcc)) << 18) + rem);
        o.x += p.x; o.y += p.y; o.z += p.z; o.w += p.w;
        l += Lpart[(size_t)(b * 4 + jcc) * 4096 + q];
    }
    const float inv = 1.0f / l;
    o.x *= inv; o.y *= inv; o.z *= inv; o.w *= inv;
    *(float4*)(out + base) = o;
}

// ---------------------------------------------------------------------------
extern "C" void kernel_launch(void* const* d_in, const int* in_sizes, int n_in,
                              void* d_out, int out_size, void* d_ws, size_t ws_size,
                              hipStream_t stream)
{
    const float* query = (const float*)d_in[0];
    const float* key_  = (const float*)d_in[1];
    const float* value = (const float*)d_in[2];
    const float* Wq    = (const float*)d_in[3];
    const float* bq    = (const float*)d_in[4];
    const float* Wk    = (const float*)d_in[5];
    const float* bk    = (const float*)d_in[6];
    const float* Wv    = (const float*)d_in[7];
    const float* bv    = (const float*)d_in[8];
    float* out = (float*)d_out;

    // ws: Qb 2MB | Kb 2MB | Vt 2MB | Opart 16MB | Lpart 256KB  (22.25MB)
    // Wt_g (384KB) ALIASES Opart: consumed by proj before attn writes Opart.
    char* ws = (char*)d_ws;
    ushort* Qb    = (ushort*)(ws);
    ushort* Kb    = (ushort*)(ws + (2  << 20));
    ushort* Vt    = (ushort*)(ws + (4  << 20));
    float*  Opart = (float*) (ws + (6  << 20));
    float*  Lpart = (float*) (ws + (22 << 20));
    ushort* Wt_g  = (ushort*)(ws + (6  << 20));

    setup_w<<<dim3(32, 3), 256, 0, stream>>>(Wq, Wk, Wv, Wt_g);
    proj_kernel<<<dim3(256, 3), 256, 0, stream>>>(
        query, key_, value, bq, bk, bv, Wt_g, Qb, Kb, Vt);
    attn_kernel<<<dim3(64, 4, 4), 256, 0, stream>>>(Qb, Kb, Vt, Opart, Lpart);
    reduce_kernel<<<dim3(1024), 256, 0, stream>>>(Opart, Lpart, out);
}

// Round 5
// 251.999 us; speedup vs baseline: 1.0292x; 1.0292x over previous
//
#include <hip/hip_runtime.h>
#include <cmath>

// B=4, S=4096, D_IN=1024, D_K=D_V=64
constexpr int B_  = 4;
constexpr int S_  = 4096;
constexpr int DIN = 1024;
constexpr int DH  = 64;

typedef short bf16x8 __attribute__((ext_vector_type(8)));
typedef float f32x4  __attribute__((ext_vector_type(4)));

#define GPTR(p) (const __attribute__((address_space(1))) unsigned int*)(p)
#define LPTR(p) (__attribute__((address_space(3))) unsigned int*)(p)

// fp32 -> bf16 RNE, raw bits
__device__ __forceinline__ ushort f2bf(float x) {
    unsigned int u = __float_as_uint(x);
    return (ushort)((u + 0x7FFFu + ((u >> 16) & 1u)) >> 16);
}

__device__ __forceinline__ bf16x8 cvt8(f32x4 a, f32x4 b) {
    union { bf16x8 v; ushort u[8]; } r;
    r.u[0] = f2bf(a[0]); r.u[1] = f2bf(a[1]); r.u[2] = f2bf(a[2]); r.u[3] = f2bf(a[3]);
    r.u[4] = f2bf(b[0]); r.u[5] = f2bf(b[1]); r.u[6] = f2bf(b[2]); r.u[7] = f2bf(b[3]);
    return r.v;
}

// softmax scale 1/8 with log2(e) folded in (softmax via exp2)
#define QSCALE 0.18033688011112042f

// ---------------------------------------------------------------------------
// setup_w: W[1024][64] fp32 -> FRAGMENT-ORDERED bf16 image (unchanged).
// Frag F = ((wi*2+ks)*4+nt)*64+lane holds the 16B MFMA B-fragment:
// W^T[n = nt*16 + (lane&15)][k = wi*64 + (ks*4 + (lane>>4))*8 + 0..7].
// ---------------------------------------------------------------------------
__global__ __launch_bounds__(256) void setup_w(
    const float* __restrict__ Wq, const float* __restrict__ Wk,
    const float* __restrict__ Wv, ushort* __restrict__ Wt_g)
{
    const int y = blockIdx.y;
    const float* W = (y == 0) ? Wq : (y == 1) ? Wk : Wv;
    const int g    = blockIdx.x * 256 + threadIdx.x;
    const int lane = g & 63;
    const int nt   = (g >> 6) & 3;
    const int ks   = (g >> 8) & 1;
    const int it   = g >> 9;
    const int m    = lane & 15;
    const int quad = lane >> 4;
    const int n    = nt * 16 + m;
    const int k0   = it * 64 + (ks * 4 + quad) * 8;
    union { uint4 q; ushort u[8]; } r;
    #pragma unroll
    for (int i = 0; i < 8; ++i) r.u[i] = f2bf(W[(size_t)(k0 + i) * DH + n]);
    *(uint4*)(Wt_g + ((size_t)y << 16) + (size_t)g * 8) = r.q;
}

// ---------------------------------------------------------------------------
// Projection v5. Post-mortem r0-r4: FIVE schedules (incl. asm-pinned 24-deep
// and 144KB/CU DMA queues) all land at 80us / 1.35TB/s -> Little's law says
// effective latency ~27us: requests queue behind a slow-served PATTERN, not a
// shallow queue. Common factor of all five: X consumed in k-windows = 256B
// per 4KB row, every row re-activated 16x -> ~4-5x DRAM burst derating
// (6.3 -> 1.35 TB/s, exactly observed). FETCH_SIZE clean = bytes right,
// bursts wrong.
//
// Fix: read each X row ONCE, full 4KB, contiguous. Two phases:
//  A) stream: wave w loads rows [w*4,w*4+4) as 32B/lane contiguous bursts
//     (wave covers 2KB/instruction-pair), cvt fp32->bf16 in regs, ds_write
//     MFMA-fragment-ordered XOR-swizzled LDS (32KB, full K for 16 rows).
//     Pure memcpy-shaped loop, no barriers -> compiler pipelines (m13 proves
//     this shape hits 6.3TB/s).
//  B) one barrier; 16 k-windows of MFMA from LDS. W fragments straight from
//     the L2-resident packed image (1KB coalesced wave-loads, depth-1
//     prefetch, no LDS, no barriers). Wave w owns output cols [w*16,w*16+16).
// 16 rows/block, 32KB LDS -> 4 blocks/CU, 16 waves/CU streaming TLP.
// ---------------------------------------------------------------------------
__global__ __launch_bounds__(256, 4) void proj_kernel(
    const float* __restrict__ Xq, const float* __restrict__ Xk, const float* __restrict__ Xv,
    const float* __restrict__ bq, const float* __restrict__ bk, const float* __restrict__ bv,
    const ushort* __restrict__ Wt_g,
    ushort* __restrict__ Qb, ushort* __restrict__ Kb, ushort* __restrict__ Vt)
{
    // xlds slot(wi,row,f): 16B at ((wi*16+row)*8 + (f ^ (row&7))) * 16
    // (XOR swizzle -> conflict-free fragment reads; V-epilogue reuses as 64x32)
    __shared__ __align__(16) ushort xlds[16384];   // 32KB

    const int y = blockIdx.y;
    const float *X, *bias;
    if (y == 0)      { X = Xq; bias = bq; }
    else if (y == 1) { X = Xk; bias = bk; }
    else             { X = Xv; bias = bv; }

    const int tid  = threadIdx.x;
    const int w    = tid >> 6;
    const int lane = tid & 63;
    const int m    = lane & 15;
    const int quad = lane >> 4;
    const int row0 = blockIdx.x * 16;

    // ---- Phase A: full-row streaming load -> bf16 -> fragment-ordered LDS
    {
        f32x4 va[8], vb[8];
        #pragma unroll
        for (int r = 0; r < 4; ++r) {
            const float* src = X + (size_t)(row0 + w * 4 + r) * DIN + lane * 8;
            #pragma unroll
            for (int sg = 0; sg < 2; ++sg) {
                va[r * 2 + sg] = *(const f32x4*)(src + sg * 512);
                vb[r * 2 + sg] = *(const f32x4*)(src + sg * 512 + 4);
            }
        }
        __builtin_amdgcn_sched_barrier(0);   // keep all 16 loads issued above
        #pragma unroll
        for (int r = 0; r < 4; ++r) {
            const int row = w * 4 + r;
            #pragma unroll
            for (int sg = 0; sg < 2; ++sg) {
                const int wi = sg * 8 + (lane >> 3);          // k-window of this frag
                const int fx = (lane & 7) ^ (row & 7);        // swizzled frag slot
                *(bf16x8*)&xlds[((wi * 16 + row) * 8 + fx) * 8] =
                    cvt8(va[r * 2 + sg], vb[r * 2 + sg]);
            }
        }
    }
    __syncthreads();

    // ---- Phase B: MFMA over 16 k-windows; W direct from L2 (packed image)
    const float bias_v = bias[w * 16 + m];
    // frag F = ((wi*2+ks)*4 + nt=w)*64 + lane -> ushort offset F*8
    const ushort* wbase = Wt_g + ((size_t)y << 16) + (size_t)(w * 64 + lane) * 8;

    f32x4 acc = {};
    bf16x8 wf0 = *(const bf16x8*)(wbase);
    bf16x8 wf1 = *(const bf16x8*)(wbase + 2048);
    #pragma unroll
    for (int wi = 0; wi < 16; ++wi) {
        bf16x8 nf0 = wf0, nf1 = wf1;
        if (wi < 15) {
            nf0 = *(const bf16x8*)(wbase + (size_t)(wi + 1) * 4096);
            nf1 = *(const bf16x8*)(wbase + (size_t)(wi + 1) * 4096 + 2048);
        }
        const bf16x8 a0 = *(const bf16x8*)&xlds[((wi * 16 + m) * 8 + ( quad      ^ (m & 7))) * 8];
        const bf16x8 a1 = *(const bf16x8*)&xlds[((wi * 16 + m) * 8 + ((4 + quad) ^ (m & 7))) * 8];
        acc = __builtin_amdgcn_mfma_f32_16x16x32_bf16(a0, wf0, acc, 0, 0, 0);
        acc = __builtin_amdgcn_mfma_f32_16x16x32_bf16(a1, wf1, acc, 0, 0, 0);
        wf0 = nf0; wf1 = nf1;
    }

    if (y < 2) {
        ushort* Out = (y == 0) ? Qb : Kb;
        const float sc = (y == 0) ? QSCALE : 1.0f;
        #pragma unroll
        for (int j = 0; j < 4; ++j) {
            const int row = row0 + quad * 4 + j;
            Out[(size_t)row * DH + w * 16 + m] = f2bf((acc[j] + bias_v) * sc);
        }
    } else {
        // V: transpose 16 rows via LDS (reuse xlds as ushort[64][32])
        __syncthreads();                     // all waves done reading xlds
        ushort (*Vx)[32] = (ushort(*)[32])xlds;
        #pragma unroll
        for (int j = 0; j < 4; ++j)
            Vx[w * 16 + m][quad * 4 + j] = f2bf(acc[j] + bias_v);
        __syncthreads();
        const int batch = row0 >> 12;
        const int s0    = row0 & 4095;
        if (tid < 128) {
            const int d = tid >> 1, h = tid & 1;
            const uint4 v = *(const uint4*)&Vx[d][h * 8];
            *(uint4*)(Vt + ((size_t)batch * 64 + d) * S_ + s0 + h * 8) = v;
        }
    }
}

// ---------------------------------------------------------------------------
// Flash attention (unchanged this round — clean A/B on proj).
// ---------------------------------------------------------------------------
__global__ __launch_bounds__(256, 4) void attn_kernel(
    const ushort* __restrict__ Qb, const ushort* __restrict__ Kb,
    const ushort* __restrict__ Vt, float* __restrict__ Opart, float* __restrict__ Lpart)
{
    __shared__ ushort Ks[64 * 64];   // [j][d], chunk-XOR swizzled
    __shared__ ushort Vs[64 * 64];   // [d][j], chunk-XOR swizzled
    __shared__ ushort Pt[64 * 72];   // per-wave stripes, padded

    const int tid  = threadIdx.x;
    const int w    = tid >> 6;
    const int lane = tid & 63;
    const int m    = lane & 15;
    const int quad = lane >> 4;
    const int b    = blockIdx.z, jc = blockIdx.y, qt = blockIdx.x;
    const int q0   = qt * 64;

    bf16x8 qf[2];
    #pragma unroll
    for (int ks = 0; ks < 2; ++ks)
        qf[ks] = *(const bf16x8*)(Qb + (size_t)(b * S_ + q0 + w * 16 + m) * 64
                                     + ks * 32 + quad * 8);

    f32x4 acc_o[4] = {};
    float Lp[4] = {};

    const ushort* kbase = Kb + (size_t)b * S_ * 64;
    const ushort* vbase = Vt + (size_t)b * 64 * S_;

    for (int it = 0; it < 16; ++it) {
        const int jt = jc * 16 + it;
        __syncthreads();
        #pragma unroll
        for (int i = 0; i < 2; ++i) {
            const int slot = w * 128 + i * 64 + lane;
            const int j = slot >> 3, c = slot & 7;
            __builtin_amdgcn_global_load_lds(
                GPTR(kbase + (size_t)(jt * 64 + j) * 64 + ((c ^ (j & 7)) * 8)),
                LPTR(&Ks[(w * 128 + i * 64) * 8]), 16, 0, 0);
            __builtin_amdgcn_global_load_lds(
                GPTR(vbase + (size_t)j * S_ + jt * 64 + ((c ^ (j & 7)) * 8)),
                LPTR(&Vs[(w * 128 + i * 64) * 8]), 16, 0, 0);
        }
        __syncthreads();

        // S2 = (Q * 0.125*log2e) K^T
        f32x4 acc_s[4] = {};
        #pragma unroll
        for (int ks = 0; ks < 2; ++ks)
            #pragma unroll
            for (int jt4 = 0; jt4 < 4; ++jt4) {
                const int j = jt4 * 16 + m;
                const bf16x8 kf = *(const bf16x8*)&Ks[j * 64 + (((ks * 4 + quad) ^ (j & 7)) * 8)];
                acc_s[jt4] = __builtin_amdgcn_mfma_f32_16x16x32_bf16(
                    qf[ks], kf, acc_s[jt4], 0, 0, 0);
            }

        // P = exp2(S2); L += rowsum; P -> per-wave LDS stripe (bf16)
        #pragma unroll
        for (int jt4 = 0; jt4 < 4; ++jt4)
            #pragma unroll
            for (int r = 0; r < 4; ++r) {
                const float e = exp2f(acc_s[jt4][r]);
                Lp[r] += e;
                Pt[(w * 16 + quad * 4 + r) * 72 + jt4 * 16 + m] = f2bf(e);
            }

        // O += P V (same-wave LDS RAW, ordered by lgkmcnt)
        #pragma unroll
        for (int jc2 = 0; jc2 < 2; ++jc2) {
            const bf16x8 pf = *(const bf16x8*)&Pt[(w * 16 + m) * 72 + jc2 * 32 + quad * 8];
            #pragma unroll
            for (int dt = 0; dt < 4; ++dt) {
                const int d = dt * 16 + m;
                const bf16x8 vf = *(const bf16x8*)&Vs[d * 64 + (((jc2 * 4 + quad) ^ (d & 7)) * 8)];
                acc_o[dt] = __builtin_amdgcn_mfma_f32_16x16x32_bf16(pf, vf, acc_o[dt], 0, 0, 0);
            }
        }
    }

    #pragma unroll
    for (int r = 0; r < 4; ++r) {
        float s = Lp[r];
        #pragma unroll
        for (int off = 1; off < 16; off <<= 1)
            s += __shfl_xor(s, off, 64);
        Lp[r] = s;
    }

    const size_t bj = (size_t)(b * 4 + jc);
    float* Ob = Opart + (bj << 18);
    #pragma unroll
    for (int dt = 0; dt < 4; ++dt)
        #pragma unroll
        for (int r = 0; r < 4; ++r) {
            const int row = q0 + w * 16 + quad * 4 + r;
            Ob[(size_t)row * 64 + dt * 16 + m] = acc_o[dt][r];
        }
    if (m == 0) {
        #pragma unroll
        for (int r = 0; r < 4; ++r)
            Lpart[bj * 4096 + q0 + w * 16 + quad * 4 + r] = Lp[r];
    }
}

// ---------------------------------------------------------------------------
// Combine j-chunk partials: out = (sum_jc O) / (sum_jc L)
// ---------------------------------------------------------------------------
__global__ __launch_bounds__(256) void reduce_kernel(
    const float* __restrict__ Opart, const float* __restrict__ Lpart, float* __restrict__ out)
{
    const int g    = blockIdx.x * 256 + threadIdx.x;
    const int base = g << 2;
    const int b    = base >> 18;
    const int rem  = base & 0x3FFFF;
    const int q    = rem >> 6;
    float4 o = make_float4(0.f, 0.f, 0.f, 0.f);
    float  l = 0.f;
    #pragma unroll
    for (int jcc = 0; jcc < 4; ++jcc) {
        const float4 p = *(const float4*)(Opart + (((size_t)(b * 4 + jcc)) << 18) + rem);
        o.x += p.x; o.y += p.y; o.z += p.z; o.w += p.w;
        l += Lpart[(size_t)(b * 4 + jcc) * 4096 + q];
    }
    const float inv = 1.0f / l;
    o.x *= inv; o.y *= inv; o.z *= inv; o.w *= inv;
    *(float4*)(out + base) = o;
}

// ---------------------------------------------------------------------------
extern "C" void kernel_launch(void* const* d_in, const int* in_sizes, int n_in,
                              void* d_out, int out_size, void* d_ws, size_t ws_size,
                              hipStream_t stream)
{
    const float* query = (const float*)d_in[0];
    const float* key_  = (const float*)d_in[1];
    const float* value = (const float*)d_in[2];
    const float* Wq    = (const float*)d_in[3];
    const float* bq    = (const float*)d_in[4];
    const float* Wk    = (const float*)d_in[5];
    const float* bk    = (const float*)d_in[6];
    const float* Wv    = (const float*)d_in[7];
    const float* bv    = (const float*)d_in[8];
    float* out = (float*)d_out;

    // ws: Qb 2MB | Kb 2MB | Vt 2MB | Opart 16MB | Lpart 256KB  (22.25MB)
    // Wt_g (384KB) ALIASES Opart: consumed by proj before attn writes Opart.
    char* ws = (char*)d_ws;
    ushort* Qb    = (ushort*)(ws);
    ushort* Kb    = (ushort*)(ws + (2  << 20));
    ushort* Vt    = (ushort*)(ws + (4  << 20));
    float*  Opart = (float*) (ws + (6  << 20));
    float*  Lpart = (float*) (ws + (22 << 20));
    ushort* Wt_g  = (ushort*)(ws + (6  << 20));

    setup_w<<<dim3(32, 3), 256, 0, stream>>>(Wq, Wk, Wv, Wt_g);
    proj_kernel<<<dim3(1024, 3), 256, 0, stream>>>(
        query, key_, value, bq, bk, bv, Wt_g, Qb, Kb, Vt);
    attn_kernel<<<dim3(64, 4, 4), 256, 0, stream>>>(Qb, Kb, Vt, Opart, Lpart);
    reduce_kernel<<<dim3(1024), 256, 0, stream>>>(Opart, Lpart, out);
}